// Round 1
// baseline (195.371 us; speedup 1.0000x reference)
//
#include <hip/hip_runtime.h>

#define B_SZ    256
#define IN_FT   4096
#define OUT_FT  4096
#define NNZ_T   500000
#define NNZ_N   100000
#define NNZ_TOT 600000

// ---- workspace layout (bytes) ----
#define OFF_XT      0u            // 4096*256 f32 = 4,194,304
#define OFF_YT      4194304u      // 4096*256 f32 = 4,194,304
#define OFF_SCOL    8388608u      // 600000 i32   = 2,400,000
#define OFF_SVAL    10788608u     // 600000 f32   = 2,400,000
#define OFF_COUNTS  13188608u     // 4096 i32
#define OFF_OFFSETS 13204992u     // 4097 i32
#define OFF_CURSOR  13221384u     // 4096 i32
#define OFF_FLAG    13237768u     // 2 i32  (flag[0]=st is int64, flag[1]=sn is int64)
// total ~12.63 MiB

// ---------------------------------------------------------------------------
// init: zero counts/cursor; block 0 detects whether idx buffers are int64
// (odd int32 words all zero since values < 4096) or int32.
__global__ __launch_bounds__(256) void k_init(const int* __restrict__ st_idx,
                                              const int* __restrict__ sn_idx,
                                              int* __restrict__ counts,
                                              int* __restrict__ cursor,
                                              int* __restrict__ flag) {
    int i = blockIdx.x * 256 + threadIdx.x;
    if (i < OUT_FT) { counts[i] = 0; cursor[i] = 0; }
    if (blockIdx.x == 0) {
        __shared__ int nz_t, nz_n;
        if (threadIdx.x == 0) { nz_t = 0; nz_n = 0; }
        __syncthreads();
        if (st_idx[2 * threadIdx.x + 1] != 0) atomicAdd(&nz_t, 1);
        if (sn_idx[2 * threadIdx.x + 1] != 0) atomicAdd(&nz_n, 1);
        __syncthreads();
        if (threadIdx.x == 0) { flag[0] = (nz_t == 0); flag[1] = (nz_n == 0); }
    }
}

// ---------------------------------------------------------------------------
// tiled transpose: in (rows x cols) -> out (cols x rows)
__global__ __launch_bounds__(256) void k_transpose(const float* __restrict__ in,
                                                   float* __restrict__ out,
                                                   int rows, int cols) {
    __shared__ float tile[32][33];
    int x0 = blockIdx.x * 32;   // col block in 'in'
    int y0 = blockIdx.y * 32;   // row block in 'in'
    int tx = threadIdx.x, ty = threadIdx.y;   // (32, 8)
    #pragma unroll
    for (int j = 0; j < 32; j += 8)
        tile[ty + j][tx] = in[(size_t)(y0 + ty + j) * cols + (x0 + tx)];
    __syncthreads();
    #pragma unroll
    for (int j = 0; j < 32; j += 8)
        out[(size_t)(x0 + ty + j) * rows + (y0 + tx)] = tile[tx][ty + j];
}

// ---------------------------------------------------------------------------
__device__ __forceinline__ void get_entry(int i,
                                          const int* __restrict__ st_idx,
                                          const float* __restrict__ st_vals,
                                          const int* __restrict__ sn_idx,
                                          const float* __restrict__ sn_vals,
                                          int stride_t, int stride_n,
                                          int& row, int& col, float& val) {
    if (i < NNZ_T) {
        row = st_idx[(size_t)i * stride_t];
        col = st_idx[(size_t)(NNZ_T + i) * stride_t];
        val = st_vals[i];
    } else {
        int j = i - NNZ_T;
        row = sn_idx[(size_t)j * stride_n];
        col = sn_idx[(size_t)(NNZ_N + j) * stride_n];
        val = sn_vals[j];
    }
}

__global__ __launch_bounds__(256) void k_hist(const int* __restrict__ st_idx,
                                              const float* __restrict__ st_vals,
                                              const int* __restrict__ sn_idx,
                                              const float* __restrict__ sn_vals,
                                              const int* __restrict__ flag,
                                              int* __restrict__ counts) {
    int i = blockIdx.x * 256 + threadIdx.x;
    if (i >= NNZ_TOT) return;
    int s_t = flag[0] ? 2 : 1, s_n = flag[1] ? 2 : 1;
    int row, col; float val;
    get_entry(i, st_idx, st_vals, sn_idx, sn_vals, s_t, s_n, row, col, val);
    atomicAdd(&counts[row], 1);
}

// ---------------------------------------------------------------------------
// exclusive scan of 4096 counts in a single 256-thread block
__global__ __launch_bounds__(256) void k_scan(const int* __restrict__ counts,
                                              int* __restrict__ offsets) {
    __shared__ int partial[256];
    int t = threadIdx.x;
    int local[16];
    int s = 0;
    #pragma unroll
    for (int j = 0; j < 16; ++j) { local[j] = counts[t * 16 + j]; s += local[j]; }
    partial[t] = s;
    __syncthreads();
    for (int d = 1; d < 256; d <<= 1) {
        int v = partial[t];
        int add = (t >= d) ? partial[t - d] : 0;
        __syncthreads();
        partial[t] = v + add;
        __syncthreads();
    }
    int base = partial[t] - s;   // exclusive prefix
    #pragma unroll
    for (int j = 0; j < 16; ++j) { offsets[t * 16 + j] = base; base += local[j]; }
    if (t == 255) offsets[4096] = partial[255];
}

// ---------------------------------------------------------------------------
__global__ __launch_bounds__(256) void k_scatter(const int* __restrict__ st_idx,
                                                 const float* __restrict__ st_vals,
                                                 const int* __restrict__ sn_idx,
                                                 const float* __restrict__ sn_vals,
                                                 const int* __restrict__ flag,
                                                 const int* __restrict__ offsets,
                                                 int* __restrict__ cursor,
                                                 int* __restrict__ scol,
                                                 float* __restrict__ sval) {
    int i = blockIdx.x * 256 + threadIdx.x;
    if (i >= NNZ_TOT) return;
    int s_t = flag[0] ? 2 : 1, s_n = flag[1] ? 2 : 1;
    int row, col; float val;
    get_entry(i, st_idx, st_vals, sn_idx, sn_vals, s_t, s_n, row, col, val);
    int pos = offsets[row] + atomicAdd(&cursor[row], 1);
    scol[pos] = col;
    sval[pos] = val;
}

// ---------------------------------------------------------------------------
// one block per output row r: yT[r, b] = sum_{nnz in row r} val * xT[col, b]
__global__ __launch_bounds__(256) void k_spmm(const float* __restrict__ xT,
                                              const int* __restrict__ scol,
                                              const float* __restrict__ sval,
                                              const int* __restrict__ offsets,
                                              float* __restrict__ yT) {
    int r = blockIdx.x;
    int t = threadIdx.x;
    int start = offsets[r], end = offsets[r + 1];
    __shared__ int   s_col[256];
    __shared__ float s_val[256];
    float acc = 0.f;
    for (int base = start; base < end; base += 256) {
        int n = min(256, end - base);
        if (t < n) { s_col[t] = scol[base + t]; s_val[t] = sval[base + t]; }
        __syncthreads();
        for (int j = 0; j < n; ++j) {
            acc += s_val[j] * xT[(size_t)s_col[j] * B_SZ + t];
        }
        __syncthreads();
    }
    yT[(size_t)r * B_SZ + t] = acc;
}

// ---------------------------------------------------------------------------
// yT (4096 x 256) -> out (256 x 4096), adding bias[r]
__global__ __launch_bounds__(256) void k_transpose_bias(const float* __restrict__ yT,
                                                        const float* __restrict__ bias,
                                                        float* __restrict__ out) {
    __shared__ float tile[32][33];
    int r0 = blockIdx.x * 32;   // out-feature block
    int b0 = blockIdx.y * 32;   // batch block
    int tx = threadIdx.x, ty = threadIdx.y;   // (32, 8)
    #pragma unroll
    for (int j = 0; j < 32; j += 8)
        tile[ty + j][tx] = yT[(size_t)(r0 + ty + j) * B_SZ + (b0 + tx)];
    __syncthreads();
    #pragma unroll
    for (int j = 0; j < 32; j += 8)
        out[(size_t)(b0 + ty + j) * OUT_FT + (r0 + tx)] = tile[tx][ty + j] + bias[r0 + tx];
}

// ---------------------------------------------------------------------------
extern "C" void kernel_launch(void* const* d_in, const int* in_sizes, int n_in,
                              void* d_out, int out_size, void* d_ws, size_t ws_size,
                              hipStream_t stream) {
    const float* x       = (const float*)d_in[0];
    const int*   st_idx  = (const int*)d_in[1];
    const float* st_vals = (const float*)d_in[2];
    const int*   sn_idx  = (const int*)d_in[3];
    const float* sn_vals = (const float*)d_in[4];
    const float* bias    = (const float*)d_in[5];
    float* out = (float*)d_out;

    char* ws = (char*)d_ws;
    float* xT      = (float*)(ws + OFF_XT);
    float* yT      = (float*)(ws + OFF_YT);
    int*   scol    = (int*)  (ws + OFF_SCOL);
    float* sval    = (float*)(ws + OFF_SVAL);
    int*   counts  = (int*)  (ws + OFF_COUNTS);
    int*   offsets = (int*)  (ws + OFF_OFFSETS);
    int*   cursor  = (int*)  (ws + OFF_CURSOR);
    int*   flag    = (int*)  (ws + OFF_FLAG);

    const int nnz_blocks = (NNZ_TOT + 255) / 256;

    k_init<<<(OUT_FT + 255) / 256, 256, 0, stream>>>(st_idx, sn_idx, counts, cursor, flag);
    k_transpose<<<dim3(IN_FT / 32, B_SZ / 32), dim3(32, 8), 0, stream>>>(x, xT, B_SZ, IN_FT);
    k_hist<<<nnz_blocks, 256, 0, stream>>>(st_idx, st_vals, sn_idx, sn_vals, flag, counts);
    k_scan<<<1, 256, 0, stream>>>(counts, offsets);
    k_scatter<<<nnz_blocks, 256, 0, stream>>>(st_idx, st_vals, sn_idx, sn_vals, flag,
                                              offsets, cursor, scol, sval);
    k_spmm<<<OUT_FT, 256, 0, stream>>>(xT, scol, sval, offsets, yT);
    k_transpose_bias<<<dim3(OUT_FT / 32, B_SZ / 32), dim3(32, 8), 0, stream>>>(yT, bias, out);
}